// Round 6
// baseline (182.675 us; speedup 1.0000x reference)
//
#include <hip/hip_runtime.h>
#include <hip/hip_bf16.h>

typedef __attribute__((ext_vector_type(8))) short short8;
typedef __attribute__((ext_vector_type(4))) float floatx4;

__device__ __forceinline__ ushort f2bf(float f) {
    union { __hip_bfloat16 h; ushort u; } cv;
    cv.h = __float2bfloat16(f);
    return cv.u;
}
__device__ __forceinline__ float bf2f(ushort u) {
    union { ushort u; __hip_bfloat16 h; } cv;
    cv.u = u;
    return __bfloat162float(cv.h);
}
// truncating f32->bf16 (RTZ): 1 shr. Used for P only (bias cancels in softmax ratio).
__device__ __forceinline__ ushort f2bf_rtz(float f) {
    union { float f; unsigned u; } cv;
    cv.f = f;
    return (ushort)(cv.u >> 16);
}

typedef __attribute__((address_space(1))) void* gas1_t;
typedef __attribute__((address_space(3))) void* las3_t;
// async global->LDS, 16B per lane. LDS dest = wave-uniform base + lane*16.
__device__ __forceinline__ void cp16(const ushort* g, ushort* l) {
    __builtin_amdgcn_global_load_lds((gas1_t)(unsigned long long)g,
                                     (las3_t)(unsigned long long)l, 16, 0, 0);
}

// ---------------------------------------------------------------------------
// Kernel 1: MERGED weight-transpose + LayerNorm (both indep preprocessing).
// ---------------------------------------------------------------------------
__global__ __launch_bounds__(256) void prep_w_ln(const float* __restrict__ Wqkv,
                                                 const float* __restrict__ Wout,
                                                 ushort* __restrict__ WqkvT,
                                                 ushort* __restrict__ WoutT,
                                                 const float* __restrict__ x,
                                                 const float* __restrict__ lw,
                                                 const float* __restrict__ lb,
                                                 ushort* __restrict__ xn) {
    const int id = blockIdx.x;
    const int tid = threadIdx.x;
    if (id < 4096) {
        __shared__ float tile[32][33];
        int bx = id & 127, by = id >> 7;
        const float* in; ushort* out; int R = 1024, C;
        if (bx < 96) { in = Wqkv; out = WqkvT; C = 3072; }
        else { in = Wout; out = WoutT; C = 1024; bx -= 96; }
        int c0 = bx * 32, r0 = by * 32;
        int tx = tid & 31, ty = tid >> 5;    // 32 x 8
        for (int j = 0; j < 32; j += 8)
            tile[ty + j][tx] = in[(size_t)(r0 + ty + j) * C + c0 + tx];
        __syncthreads();
        for (int j = 0; j < 32; j += 8)
            out[(size_t)(c0 + ty + j) * R + r0 + tx] = f2bf(tile[tx][ty + j]);
    } else {
        int row = id - 4096;
        const float4* xr = (const float4*)(x + (size_t)row * 1024);
        float4 v = xr[tid];
        float s = v.x + v.y + v.z + v.w;
        float sq = v.x * v.x + v.y * v.y + v.z * v.z + v.w * v.w;
        for (int off = 32; off; off >>= 1) {
            s += __shfl_xor(s, off);
            sq += __shfl_xor(sq, off);
        }
        __shared__ float ls[4], lq[4];
        int wave = tid >> 6, lane = tid & 63;
        if (lane == 0) { ls[wave] = s; lq[wave] = sq; }
        __syncthreads();
        s = ls[0] + ls[1] + ls[2] + ls[3];
        sq = lq[0] + lq[1] + lq[2] + lq[3];
        float mu = s * (1.0f / 1024.0f);
        float var = sq * (1.0f / 1024.0f) - mu * mu;
        float rs = rsqrtf(var + 1e-5f);
        const float4* wr = (const float4*)lw;
        const float4* br = (const float4*)lb;
        float4 wv = wr[tid], bv = br[tid];
        ushort4 o;
        o.x = f2bf((v.x - mu) * rs * wv.x + bv.x);
        o.y = f2bf((v.y - mu) * rs * wv.y + bv.y);
        o.z = f2bf((v.z - mu) * rs * wv.z + bv.z);
        o.w = f2bf((v.w - mu) * rs * wv.w + bv.w);
        *(ushort4*)&xn[(size_t)row * 1024 + tid * 4] = o;
    }
}

// ---------------------------------------------------------------------------
// Kernel 2: FUSED QKV GEMM, XCD-striped grid (1-D 768).
// ---------------------------------------------------------------------------
__global__ __launch_bounds__(256) void gemm_qkv_fused(const ushort* __restrict__ A,
                                                      const ushort* __restrict__ Bt,
                                                      ushort* __restrict__ Qt,
                                                      ushort* __restrict__ Kt,
                                                      ushort* __restrict__ Vb) {
    __shared__ ushort smem[18432];
    const int K = 1024, T = 32;
    const int id = blockIdx.x;
    const int xcd = id & 7, r_ = id >> 3;
    const int bm = (xcd * 4 + r_ / 24) * 128;
    const int bn = r_ % 24;
    const int tid = threadIdx.x;
    const int wave = tid >> 6, lane = tid & 63;
    const int quad = lane >> 4, l15 = lane & 15;
    const int wm = (wave >> 1) * 64, wn = (wave & 1) * 64;

    const int s0 = tid, s1 = tid + 256;
    const int row0 = s0 >> 2, src0 = (s0 & 3) ^ (row0 & 3);
    const int row1 = s1 >> 2, src1 = (s1 & 3) ^ (row1 & 3);

    floatx4 acc[4][4];
    floatx4 z4 = {0.f, 0.f, 0.f, 0.f};
    for (int mi = 0; mi < 4; mi++)
        for (int ni = 0; ni < 4; ni++) acc[mi][ni] = z4;

    const ushort* Ap0 = A + (size_t)(bm + row0) * K + src0 * 8;
    const ushort* Ap1 = A + (size_t)(bm + row1) * K + src1 * 8;
    const ushort* Bp0 = Bt + (size_t)(bn * 128 + row0) * K + src0 * 8;
    const ushort* Bp1 = Bt + (size_t)(bn * 128 + row1) * K + src1 * 8;

    ushort* As = smem;          // [2][4096]
    ushort* Bs = smem + 8192;   // [2][4096]

    cp16(Ap0, &As[wave * 512]);
    cp16(Ap1, &As[2048 + wave * 512]);
    cp16(Bp0, &Bs[wave * 512]);
    cp16(Bp1, &Bs[2048 + wave * 512]);

    for (int t = 0; t < T; t++) {
        __syncthreads();
        if (t + 1 < T) {
            const int nb = (t + 1) & 1;
            const int k0n = (t + 1) << 5;
            cp16(Ap0 + k0n, &As[nb * 4096 + wave * 512]);
            cp16(Ap1 + k0n, &As[nb * 4096 + 2048 + wave * 512]);
            cp16(Bp0 + k0n, &Bs[nb * 4096 + wave * 512]);
            cp16(Bp1 + k0n, &Bs[nb * 4096 + 2048 + wave * 512]);
        }
        const ushort* Ab = As + (t & 1) * 4096;
        const ushort* Bb = Bs + (t & 1) * 4096;
        short8 af[4], bfr[4];
        for (int mi = 0; mi < 4; mi++) {
            int ra = wm + mi * 16 + l15;
            af[mi] = *(const short8*)&Ab[ra * 32 + ((quad ^ (ra & 3)) << 3)];
        }
        for (int ni = 0; ni < 4; ni++) {
            int rb = wn + ni * 16 + l15;
            bfr[ni] = *(const short8*)&Bb[rb * 32 + ((quad ^ (rb & 3)) << 3)];
        }
        for (int mi = 0; mi < 4; mi++)
            for (int ni = 0; ni < 4; ni++)
                acc[mi][ni] = __builtin_amdgcn_mfma_f32_16x16x32_bf16(
                    af[mi], bfr[ni], acc[mi][ni], 0, 0, 0);
    }

    const int col_base = bn * 128 + wn;
    const int type = col_base >> 10;             // 0=q, 1=k, 2=v
    const int h = (col_base & 1023) >> 6;
    const int row_base = bm + wm;

    if (type < 2) {
        ushort* dst = (type == 0) ? Qt : Kt;
        for (int mi = 0; mi < 4; mi++) {
            for (int r = 0; r < 4; r++) {
                float ss = 0.f;
                for (int ni = 0; ni < 4; ni++) ss += acc[mi][ni][r] * acc[mi][ni][r];
                for (int off = 1; off < 16; off <<= 1) ss += __shfl_xor(ss, off);
                float inv = rsqrtf(fmaxf(ss, 1e-24f));
                int rg = row_base + mi * 16 + quad * 4 + r;
                int bb = rg >> 11, n = rg & 2047;
                size_t orow = ((size_t)(bb * 16 + h) * 2048 + n) * 64;
                for (int ni = 0; ni < 4; ni++)
                    dst[orow + ni * 16 + l15] = f2bf(acc[mi][ni][r] * inv);
            }
        }
    } else {
        __syncthreads();
        ushort* tr = smem + wave * 4608;   // 64 x 72
        for (int mi = 0; mi < 4; mi++)
            for (int ni = 0; ni < 4; ni++)
                for (int r = 0; r < 4; r++) {
                    int row_l = mi * 16 + quad * 4 + r;   // n_loc
                    int col_l = ni * 16 + l15;            // d
                    tr[col_l * 72 + row_l] = f2bf(acc[mi][ni][r]);
                }
        int bb = row_base >> 11, n0 = row_base & 2047;
        size_t vbase = ((size_t)(bb * 16 + h) * 32 + (n0 >> 6)) * 4096;
        const int dl = lane >> 3, nc = (lane & 7) * 8;
        for (int i = 0; i < 8; i++) {
            int d = dl + i * 8;
            short8 val = *(const short8*)&tr[d * 72 + nc];
            *(short8*)&Vb[vbase + (size_t)d * 64 + nc] = val;
        }
    }
}

// ---------------------------------------------------------------------------
// Kernel 3: MFMA GEMM (out-proj) — 64x64 tiles, BK=64, grid 1024 = 4/CU.
// (round-5 passing version, unchanged)
// ---------------------------------------------------------------------------
__global__ __launch_bounds__(256) void gemm_out(const ushort* __restrict__ A,
                                                const ushort* __restrict__ Bt,
                                                float* __restrict__ C) {
    __shared__ ushort As[2][4096];
    __shared__ ushort Bs[2][4096];
    const int K = 1024, N = 1024;
    const int id = blockIdx.x;             // 0..1023
    const int xcd = id & 7, r_ = id >> 3;  // r_ 0..127
    const int bm = (xcd * 8 + (r_ >> 4)) * 64;
    const int bn = (r_ & 15) * 64;
    const int tid = threadIdx.x;
    const int wave = tid >> 6, lane = tid & 63;
    const int quad = lane >> 4, l15 = lane & 15;
    const int wm = (wave >> 1) * 32, wn = (wave & 1) * 32;

    // staging: rows of 64 ushorts (128B = 8 chunks), chunk-XOR pre-swizzled src
    const int ch0 = tid, ch1 = tid + 256;
    const int r0 = ch0 >> 3, sg0 = (ch0 & 7) ^ (r0 & 7);
    const int r1 = ch1 >> 3, sg1 = (ch1 & 7) ^ (r1 & 7);

    floatx4 acc[2][2];
    floatx4 z4 = {0.f, 0.f, 0.f, 0.f};
    for (int mi = 0; mi < 2; mi++)
        for (int ni = 0; ni < 2; ni++) acc[mi][ni] = z4;

    const ushort* Ap0 = A + (size_t)(bm + r0) * K + sg0 * 8;
    const ushort* Ap1 = A + (size_t)(bm + r1) * K + sg1 * 8;
    const ushort* Bp0 = Bt + (size_t)(bn + r0) * K + sg0 * 8;
    const ushort* Bp1 = Bt + (size_t)(bn + r1) * K + sg1 * 8;

    const int T = 16;                      // K/64
    cp16(Ap0, &As[0][wave * 512]);
    cp16(Ap1, &As[0][2048 + wave * 512]);
    cp16(Bp0, &Bs[0][wave * 512]);
    cp16(Bp1, &Bs[0][2048 + wave * 512]);

    for (int t = 0; t < T; t++) {
        __syncthreads();
        if (t + 1 < T) {
            const int nb = (t + 1) & 1;
            const int k0n = (t + 1) << 6;
            cp16(Ap0 + k0n, &As[nb][wave * 512]);
            cp16(Ap1 + k0n, &As[nb][2048 + wave * 512]);
            cp16(Bp0 + k0n, &Bs[nb][wave * 512]);
            cp16(Bp1 + k0n, &Bs[nb][2048 + wave * 512]);
        }
        const ushort* Ab = As[t & 1];
        const ushort* Bb = Bs[t & 1];
        short8 a0[2], a1[2], b0[2], b1[2];
        for (int mi = 0; mi < 2; mi++) {
            int ra = wm + mi * 16 + l15;
            a0[mi] = *(const short8*)&Ab[ra * 64 + ((quad ^ (ra & 7)) << 3)];
            a1[mi] = *(const short8*)&Ab[ra * 64 + (((quad + 4) ^ (ra & 7)) << 3)];
        }
        for (int ni = 0; ni < 2; ni++) {
            int rb = wn + ni * 16 + l15;
            b0[ni] = *(const short8*)&Bb[rb * 64 + ((quad ^ (rb & 7)) << 3)];
            b1[ni] = *(const short8*)&Bb[rb * 64 + (((quad + 4) ^ (rb & 7)) << 3)];
        }
        for (int mi = 0; mi < 2; mi++)
            for (int ni = 0; ni < 2; ni++) {
                acc[mi][ni] = __builtin_amdgcn_mfma_f32_16x16x32_bf16(
                    a0[mi], b0[ni], acc[mi][ni], 0, 0, 0);
                acc[mi][ni] = __builtin_amdgcn_mfma_f32_16x16x32_bf16(
                    a1[mi], b1[ni], acc[mi][ni], 0, 0, 0);
            }
    }
    for (int mi = 0; mi < 2; mi++)
        for (int ni = 0; ni < 2; ni++)
            for (int r = 0; r < 4; r++) {
                int row = bm + wm + mi * 16 + quad * 4 + r;
                int col = bn + wn + ni * 16 + l15;
                C[(size_t)row * N + col] = acc[mi][ni][r];
            }
}

// ---------------------------------------------------------------------------
// Kernel 4: causal flash attention v17 — SPLIT-K makespan attack. Evidence
// (rounds 0-5): flash dur == max-units-per-block x ~1.4us regardless of
// grid/LDS/occupancy -> chain-latency-bound. Fix: qt>=16 computed by 2
// blocks (kv halves <=16 units); qt<=15 whole (<=16 units). Fixed-max
// softmax -> partials combine by pure addition (no rescale). Partial O (f32)
// in d_out scratch (dead until gemm_out rewrites all), RS in dead-WqkvT ws.
// FTAB[48]: every round-robin co-resident group of 6 sums to exactly 66
// units (all 48 (qt,half) slots appear exactly once). Grid 1536.
// entry = qt | ks<<8 | ke<<16 (kv64-tile units), index v = (s<<3)|w.
// ---------------------------------------------------------------------------
#define LOG2E8 11.541560327111707f   // 8 * log2(e)

__constant__ unsigned FTAB[48] = {
    // s=0
    0x0010000Fu, 0x00020001u, 0x000F001Du, 0x00120911u,
    0x000D0019u, 0x00060005u, 0x000E001Au, 0x00080007u,
    // s=1
    0x000F000Eu, 0x00130A12u, 0x0020101Fu, 0x00040003u,
    0x00110910u, 0x001C0E1Bu, 0x00070006u, 0x000C0017u,
    // s=2
    0x000E000Du, 0x000A0009u, 0x00030002u, 0x0010001Eu,
    0x000F001Cu, 0x001A0D19u, 0x000D0018u, 0x00180C17u,
    // s=3
    0x000B000Au, 0x0010001Fu, 0x000D000Cu, 0x001E0F1Du,
    0x00050004u, 0x000C000Bu, 0x00190D18u, 0x00160B15u,
    // s=4
    0x00090008u, 0x001F101Eu, 0x00150B14u, 0x00090010u,
    0x000E001Bu, 0x000B0015u, 0x00140A13u, 0x000C0016u,
    // s=5
    0x00010000u, 0x001D0F1Cu, 0x00090011u, 0x001B0E1Au,
    0x00170C16u, 0x000A0013u, 0x000A0012u, 0x000B0014u
};

__global__ __launch_bounds__(256) void flash_attn(const ushort* __restrict__ Qt,
                                                  const ushort* __restrict__ Kt,
                                                  const ushort* __restrict__ Vb,
                                                  ushort* __restrict__ O,
                                                  float* __restrict__ Opart,
                                                  float* __restrict__ RSpart) {
    const int id = blockIdx.x;             // 0..1535
    const int xcd = id & 7, r_ = id >> 3;  // r_ 0..191
    const int bh = xcd + ((r_ & 3) << 3);  // 4 bh per XCD (fixed per CU)
    const unsigned e = FTAB[r_ >> 2];      // v in [0,48)
    const int qt = e & 255;
    const int ks = (e >> 8) & 255;
    const int ke = (int)(e >> 16);
    const int b = bh >> 4, h = bh & 15;
    const int tid = threadIdx.x;
    const int wave = tid >> 6, lane = tid & 63;
    const int quad = lane >> 4, l15 = lane & 15;

    __shared__ ushort Ks[2][64 * 64];   // 16 KB double-buffered K
    __shared__ ushort Vs[64 * 64];      //  8 KB single-buffered V
    __shared__ ushort Ps[4][16 * 64];   //  8 KB, stride 64, chunk-XOR swizzled

    const int ch0 = tid, ch1 = tid + 256;
    const int r0 = ch0 >> 3, sg0 = (ch0 & 7) ^ (r0 & 7);
    const int r1 = ch1 >> 3, sg1 = (ch1 & 7) ^ (r1 & 7);

    const ushort* Kp0 = Kt + ((size_t)bh * 2048 + r0) * 64 + sg0 * 8;
    const ushort* Kp1 = Kt + ((size_t)bh * 2048 + r1) * 64 + sg1 * 8;
    const ushort* Vp0 = Vb + (size_t)bh * 131072 + r0 * 64 + sg0 * 8;
    const ushort* Vp1 = Vb + (size_t)bh * 131072 + r1 * 64 + sg1 * 8;

    floatx4 z4 = {0.f, 0.f, 0.f, 0.f};

    const int q0 = qt * 64;
    const ushort* Qp = Qt + ((size_t)bh * 2048 + q0 + wave * 16 + l15) * 64;
    short8 qf0 = *(const short8*)(Qp + quad * 8);
    short8 qf1 = *(const short8*)(Qp + 32 + quad * 8);

    float rs_acc[4] = {0.f, 0.f, 0.f, 0.f};
    floatx4 o_acc[4];
    for (int ni = 0; ni < 4; ni++) o_acc[ni] = z4;

    // prologue: K[ks] via cp16 (async), V[ks] into registers
    const size_t o0 = (size_t)ks * 4096;
    cp16(Kp0 + o0, &Ks[ks & 1][wave * 512]);
    cp16(Kp1 + o0, &Ks[ks & 1][2048 + wave * 512]);
    short8 vA = *(const short8*)(Vp0 + o0);
    short8 vB = *(const short8*)(Vp1 + o0);

    for (int kt = ks; kt < ke; kt++) {
        __syncthreads();                     // K[kt] published; prior PV done
        // publish V[kt] from registers (compiler waits vmcnt for vA/vB)
        *(short8*)&Vs[(unsigned)tid * 8] = vA;
        *(short8*)&Vs[(unsigned)(tid + 256) * 8] = vB;
        if (kt + 1 < ke) {                   // prefetch kt+1 during compute
            const int nb2 = (kt + 1) & 1;
            const size_t to = (size_t)(kt + 1) * 4096;
            cp16(Kp0 + to, &Ks[nb2][wave * 512]);
            cp16(Kp1 + to, &Ks[nb2][2048 + wave * 512]);
            vA = *(const short8*)(Vp0 + to);
            vB = *(const short8*)(Vp1 + to);
        }
        const ushort* Kb = Ks[kt & 1];

        floatx4 s_acc[4];
        for (int ni = 0; ni < 4; ni++) s_acc[ni] = z4;
        for (int ni = 0; ni < 4; ni++) {
            int rb = ni * 16 + l15;
            short8 kf0 = *(const short8*)&Kb[rb * 64 + ((quad ^ (rb & 7)) << 3)];
            short8 kf1 = *(const short8*)&Kb[rb * 64 + (((quad + 4) ^ (rb & 7)) << 3)];
            s_acc[ni] = __builtin_amdgcn_mfma_f32_16x16x32_bf16(qf0, kf0, s_acc[ni], 0, 0, 0);
            s_acc[ni] = __builtin_amdgcn_mfma_f32_16x16x32_bf16(qf1, kf1, s_acc[ni], 0, 0, 0);
        }

        const bool diag = (kt == qt);
        for (int ni = 0; ni < 4; ni++) {
            const int col_loc = ni * 16 + l15;
            const int chnk = col_loc >> 3;
            for (int r = 0; r < 4; r++) {
                const int row_l = quad * 4 + r;
                float e2 = __builtin_amdgcn_exp2f(
                    fmaf(s_acc[ni][r], LOG2E8, -LOG2E8));
                if (diag && col_loc > wave * 16 + row_l) e2 = 0.f;
                rs_acc[r] += e2;
                Ps[wave][row_l * 64 + (((chnk ^ (row_l & 7)) << 3) | (col_loc & 7))] =
                    f2bf_rtz(e2);
            }
        }

        __syncthreads();                     // V[kt] stores visible to all waves

        short8 pa0 = *(const short8*)&Ps[wave][l15 * 64 + ((quad ^ (l15 & 7)) << 3)];
        short8 pa1 = *(const short8*)&Ps[wave][l15 * 64 + (((quad + 4) ^ (l15 & 7)) << 3)];
        for (int ni = 0; ni < 4; ni++) {
            int rv = ni * 16 + l15;
            short8 v0 = *(const short8*)&Vs[rv * 64 + ((quad ^ (rv & 7)) << 3)];
            short8 v1 = *(const short8*)&Vs[rv * 64 + (((quad + 4) ^ (rv & 7)) << 3)];
            o_acc[ni] = __builtin_amdgcn_mfma_f32_16x16x32_bf16(pa0, v0, o_acc[ni], 0, 0, 0);
            o_acc[ni] = __builtin_amdgcn_mfma_f32_16x16x32_bf16(pa1, v1, o_acc[ni], 0, 0, 0);
        }
    }

    if (qt < 16) {
        // whole q-tile: normalize and write O rows n < 1024 directly
        for (int r = 0; r < 4; r++) {
            float rs = rs_acc[r];
            for (int off = 1; off < 16; off <<= 1) rs += __shfl_xor(rs, off);
            float inv = 1.0f / rs;
            int grow = q0 + wave * 16 + quad * 4 + r;
            size_t rowbase = ((size_t)b * 2048 + grow) * 1024 + h * 64;
            for (int ni = 0; ni < 4; ni++)
                O[rowbase + ni * 16 + l15] = f2bf(o_acc[ni][r] * inv);
        }
    } else {
        // split half: write f32 partials (O-sum and row-sum); combine adds.
        const int half = (ks != 0) ? 1 : 0;
        float* Oh = Opart + (size_t)half * 2097152
                  + (size_t)(bh * 16 + (qt - 16)) * 4096;
        float* RSp = RSpart + half * 32768 + (bh * 16 + (qt - 16)) * 64;
        for (int r = 0; r < 4; r++) {
            float rs = rs_acc[r];
            for (int off = 1; off < 16; off <<= 1) rs += __shfl_xor(rs, off);
            int rloc = wave * 16 + quad * 4 + r;
            if (l15 == 0) RSp[rloc] = rs;
            for (int ni = 0; ni < 4; ni++)
                Oh[rloc * 64 + ni * 16 + l15] = o_acc[ni][r];
        }
    }
}

// ---------------------------------------------------------------------------
// Kernel 5: combine split-k partials -> O rows n >= 1024. 4 rows/block.
// ---------------------------------------------------------------------------
__global__ __launch_bounds__(256) void combine(const float* __restrict__ Opart,
                                               const float* __restrict__ RSpart,
                                               ushort* __restrict__ O) {
    const int row = blockIdx.x * 4 + (threadIdx.x >> 6);   // 0..32767
    const int d = threadIdx.x & 63;
    const float inv = 1.0f / (RSpart[row] + RSpart[32768 + row]);
    const float o = Opart[(size_t)row * 64 + d]
                  + Opart[2097152 + (size_t)row * 64 + d];
    const int bh = row >> 10;              // 1024 rows per bh
    const int b = bh >> 4, h = bh & 15;
    const int n = 1024 + (row & 1023);     // qt>=16 -> n in [1024, 2048)
    O[((size_t)b * 2048 + n) * 1024 + h * 64 + d] = f2bf(o * inv);
}

// ---------------------------------------------------------------------------
extern "C" void kernel_launch(void* const* d_in, const int* in_sizes, int n_in,
                              void* d_out, int out_size, void* d_ws, size_t ws_size,
                              hipStream_t stream) {
    const float* x = (const float*)d_in[0];
    const float* ln_w = (const float*)d_in[1];
    const float* ln_b = (const float*)d_in[2];
    const float* W_qkv = (const float*)d_in[3];
    const float* W_out = (const float*)d_in[4];

    char* w = (char*)d_ws;
    // obuf ALIASES xn: xn is dead after gemm_qkv_fused's last read; flash
    // writes obuf strictly afterwards (stream-ordered). ws = 40 MiB.
    // Split-k scratch: Opart (2x8 MiB f32) lives in d_out (dead until
    // gemm_out overwrites every element); RSpart (256 KB) in dead-WqkvT.
    ushort* xn    = (ushort*)(w);                          // 8 MiB
    ushort* obuf  = (ushort*)(w);                          // 8 MiB (alias)
    ushort* WqkvT = (ushort*)(w + (8ull << 20));           // 6 MiB
    ushort* WoutT = (ushort*)(w + (14ull << 20));          // 2 MiB
    ushort* Vb    = (ushort*)(w + (16ull << 20));          // 8 MiB
    ushort* Qt    = (ushort*)(w + (24ull << 20));          // 8 MiB
    ushort* Kt    = (ushort*)(w + (32ull << 20));          // 8 MiB -> 40 MiB total
    float*  Opart  = (float*)d_out;                        // 16 MiB scratch
    float*  RSpart = (float*)(w + (8ull << 20));           // 256 KB (dead WqkvT)

    prep_w_ln<<<8192, 256, 0, stream>>>(W_qkv, W_out, WqkvT, WoutT, x, ln_w, ln_b, xn);
    gemm_qkv_fused<<<768, 256, 0, stream>>>(xn, WqkvT, Qt, Kt, Vb);
    flash_attn<<<1536, 256, 0, stream>>>(Qt, Kt, Vb, obuf, Opart, RSpart);
    combine<<<8192, 256, 0, stream>>>(Opart, RSpart, obuf);
    gemm_out<<<1024, 256, 0, stream>>>(obuf, WoutT, (float*)d_out);
}

// Round 9
// 172.528 us; speedup vs baseline: 1.0588x; 1.0588x over previous
//
#include <hip/hip_runtime.h>
#include <hip/hip_bf16.h>

typedef __attribute__((ext_vector_type(8))) short short8;
typedef __attribute__((ext_vector_type(4))) float floatx4;

__device__ __forceinline__ ushort f2bf(float f) {
    union { __hip_bfloat16 h; ushort u; } cv;
    cv.h = __float2bfloat16(f);
    return cv.u;
}
__device__ __forceinline__ float bf2f(ushort u) {
    union { ushort u; __hip_bfloat16 h; } cv;
    cv.u = u;
    return __bfloat162float(cv.h);
}
// truncating f32->bf16 (RTZ): 1 shr. Used for P only (bias cancels in softmax ratio).
__device__ __forceinline__ ushort f2bf_rtz(float f) {
    union { float f; unsigned u; } cv;
    cv.f = f;
    return (ushort)(cv.u >> 16);
}

typedef __attribute__((address_space(1))) void* gas1_t;
typedef __attribute__((address_space(3))) void* las3_t;
// async global->LDS, 16B per lane. LDS dest = wave-uniform base + lane*16.
__device__ __forceinline__ void cp16(const ushort* g, ushort* l) {
    __builtin_amdgcn_global_load_lds((gas1_t)(unsigned long long)g,
                                     (las3_t)(unsigned long long)l, 16, 0, 0);
}

// ---------------------------------------------------------------------------
// Kernel 1: MERGED weight-transpose + LayerNorm (both indep preprocessing).
// ---------------------------------------------------------------------------
__global__ __launch_bounds__(256) void prep_w_ln(const float* __restrict__ Wqkv,
                                                 const float* __restrict__ Wout,
                                                 ushort* __restrict__ WqkvT,
                                                 ushort* __restrict__ WoutT,
                                                 const float* __restrict__ x,
                                                 const float* __restrict__ lw,
                                                 const float* __restrict__ lb,
                                                 ushort* __restrict__ xn) {
    const int id = blockIdx.x;
    const int tid = threadIdx.x;
    if (id < 4096) {
        __shared__ float tile[32][33];
        int bx = id & 127, by = id >> 7;
        const float* in; ushort* out; int R = 1024, C;
        if (bx < 96) { in = Wqkv; out = WqkvT; C = 3072; }
        else { in = Wout; out = WoutT; C = 1024; bx -= 96; }
        int c0 = bx * 32, r0 = by * 32;
        int tx = tid & 31, ty = tid >> 5;    // 32 x 8
        for (int j = 0; j < 32; j += 8)
            tile[ty + j][tx] = in[(size_t)(r0 + ty + j) * C + c0 + tx];
        __syncthreads();
        for (int j = 0; j < 32; j += 8)
            out[(size_t)(c0 + ty + j) * R + r0 + tx] = f2bf(tile[tx][ty + j]);
    } else {
        int row = id - 4096;
        const float4* xr = (const float4*)(x + (size_t)row * 1024);
        float4 v = xr[tid];
        float s = v.x + v.y + v.z + v.w;
        float sq = v.x * v.x + v.y * v.y + v.z * v.z + v.w * v.w;
        for (int off = 32; off; off >>= 1) {
            s += __shfl_xor(s, off);
            sq += __shfl_xor(sq, off);
        }
        __shared__ float ls[4], lq[4];
        int wave = tid >> 6, lane = tid & 63;
        if (lane == 0) { ls[wave] = s; lq[wave] = sq; }
        __syncthreads();
        s = ls[0] + ls[1] + ls[2] + ls[3];
        sq = lq[0] + lq[1] + lq[2] + lq[3];
        float mu = s * (1.0f / 1024.0f);
        float var = sq * (1.0f / 1024.0f) - mu * mu;
        float rs = rsqrtf(var + 1e-5f);
        const float4* wr = (const float4*)lw;
        const float4* br = (const float4*)lb;
        float4 wv = wr[tid], bv = br[tid];
        ushort4 o;
        o.x = f2bf((v.x - mu) * rs * wv.x + bv.x);
        o.y = f2bf((v.y - mu) * rs * wv.y + bv.y);
        o.z = f2bf((v.z - mu) * rs * wv.z + bv.z);
        o.w = f2bf((v.w - mu) * rs * wv.w + bv.w);
        *(ushort4*)&xn[(size_t)row * 1024 + tid * 4] = o;
    }
}

// ---------------------------------------------------------------------------
// Kernel 2: FUSED QKV GEMM, XCD-striped grid (1-D 768).
// ---------------------------------------------------------------------------
__global__ __launch_bounds__(256) void gemm_qkv_fused(const ushort* __restrict__ A,
                                                      const ushort* __restrict__ Bt,
                                                      ushort* __restrict__ Qt,
                                                      ushort* __restrict__ Kt,
                                                      ushort* __restrict__ Vb) {
    __shared__ ushort smem[18432];
    const int K = 1024, T = 32;
    const int id = blockIdx.x;
    const int xcd = id & 7, r_ = id >> 3;
    const int bm = (xcd * 4 + r_ / 24) * 128;
    const int bn = r_ % 24;
    const int tid = threadIdx.x;
    const int wave = tid >> 6, lane = tid & 63;
    const int quad = lane >> 4, l15 = lane & 15;
    const int wm = (wave >> 1) * 64, wn = (wave & 1) * 64;

    const int s0 = tid, s1 = tid + 256;
    const int row0 = s0 >> 2, src0 = (s0 & 3) ^ (row0 & 3);
    const int row1 = s1 >> 2, src1 = (s1 & 3) ^ (row1 & 3);

    floatx4 acc[4][4];
    floatx4 z4 = {0.f, 0.f, 0.f, 0.f};
    for (int mi = 0; mi < 4; mi++)
        for (int ni = 0; ni < 4; ni++) acc[mi][ni] = z4;

    const ushort* Ap0 = A + (size_t)(bm + row0) * K + src0 * 8;
    const ushort* Ap1 = A + (size_t)(bm + row1) * K + src1 * 8;
    const ushort* Bp0 = Bt + (size_t)(bn * 128 + row0) * K + src0 * 8;
    const ushort* Bp1 = Bt + (size_t)(bn * 128 + row1) * K + src1 * 8;

    ushort* As = smem;          // [2][4096]
    ushort* Bs = smem + 8192;   // [2][4096]

    cp16(Ap0, &As[wave * 512]);
    cp16(Ap1, &As[2048 + wave * 512]);
    cp16(Bp0, &Bs[wave * 512]);
    cp16(Bp1, &Bs[2048 + wave * 512]);

    for (int t = 0; t < T; t++) {
        __syncthreads();
        if (t + 1 < T) {
            const int nb = (t + 1) & 1;
            const int k0n = (t + 1) << 5;
            cp16(Ap0 + k0n, &As[nb * 4096 + wave * 512]);
            cp16(Ap1 + k0n, &As[nb * 4096 + 2048 + wave * 512]);
            cp16(Bp0 + k0n, &Bs[nb * 4096 + wave * 512]);
            cp16(Bp1 + k0n, &Bs[nb * 4096 + 2048 + wave * 512]);
        }
        const ushort* Ab = As + (t & 1) * 4096;
        const ushort* Bb = Bs + (t & 1) * 4096;
        short8 af[4], bfr[4];
        for (int mi = 0; mi < 4; mi++) {
            int ra = wm + mi * 16 + l15;
            af[mi] = *(const short8*)&Ab[ra * 32 + ((quad ^ (ra & 3)) << 3)];
        }
        for (int ni = 0; ni < 4; ni++) {
            int rb = wn + ni * 16 + l15;
            bfr[ni] = *(const short8*)&Bb[rb * 32 + ((quad ^ (rb & 3)) << 3)];
        }
        for (int mi = 0; mi < 4; mi++)
            for (int ni = 0; ni < 4; ni++)
                acc[mi][ni] = __builtin_amdgcn_mfma_f32_16x16x32_bf16(
                    af[mi], bfr[ni], acc[mi][ni], 0, 0, 0);
    }

    const int col_base = bn * 128 + wn;
    const int type = col_base >> 10;             // 0=q, 1=k, 2=v
    const int h = (col_base & 1023) >> 6;
    const int row_base = bm + wm;

    if (type < 2) {
        ushort* dst = (type == 0) ? Qt : Kt;
        for (int mi = 0; mi < 4; mi++) {
            for (int r = 0; r < 4; r++) {
                float ss = 0.f;
                for (int ni = 0; ni < 4; ni++) ss += acc[mi][ni][r] * acc[mi][ni][r];
                for (int off = 1; off < 16; off <<= 1) ss += __shfl_xor(ss, off);
                float inv = rsqrtf(fmaxf(ss, 1e-24f));
                int rg = row_base + mi * 16 + quad * 4 + r;
                int bb = rg >> 11, n = rg & 2047;
                size_t orow = ((size_t)(bb * 16 + h) * 2048 + n) * 64;
                for (int ni = 0; ni < 4; ni++)
                    dst[orow + ni * 16 + l15] = f2bf(acc[mi][ni][r] * inv);
            }
        }
    } else {
        __syncthreads();
        ushort* tr = smem + wave * 4608;   // 64 x 72
        for (int mi = 0; mi < 4; mi++)
            for (int ni = 0; ni < 4; ni++)
                for (int r = 0; r < 4; r++) {
                    int row_l = mi * 16 + quad * 4 + r;   // n_loc
                    int col_l = ni * 16 + l15;            // d
                    tr[col_l * 72 + row_l] = f2bf(acc[mi][ni][r]);
                }
        int bb = row_base >> 11, n0 = row_base & 2047;
        size_t vbase = ((size_t)(bb * 16 + h) * 32 + (n0 >> 6)) * 4096;
        const int dl = lane >> 3, nc = (lane & 7) * 8;
        for (int i = 0; i < 8; i++) {
            int d = dl + i * 8;
            short8 val = *(const short8*)&tr[d * 72 + nc];
            *(short8*)&Vb[vbase + (size_t)d * 64 + nc] = val;
        }
    }
}

// ---------------------------------------------------------------------------
// Kernel 3: MFMA GEMM (out-proj) — 128x64 tiles, BK=64, grid 512 (2/CU at
// 48KB LDS), 16 MFMA/wave/step. Attribution experiment: this is the ONLY
// change vs the round-5 passing pipeline. Round 3 ran this kernel (values
// passed, absmax 0.0234) bundled with 2 flash changes; if the line-490-class
// failure recurs HERE, this kernel is convicted and dropped.
// ---------------------------------------------------------------------------
__global__ __launch_bounds__(256) void gemm_out(const ushort* __restrict__ A,
                                                const ushort* __restrict__ Bt,
                                                float* __restrict__ C) {
    __shared__ ushort As[2][8192];         // 128 rows x 64 k
    __shared__ ushort Bs[2][4096];         // 64 rows x 64 k
    const int K = 1024, N = 1024;
    const int id = blockIdx.x;             // 0..511
    const int xcd = id & 7, r_ = id >> 3;  // 0..63
    const int bm = (xcd * 4 + (r_ >> 4)) * 128;   // 32 m-tiles
    const int bn = (r_ & 15) * 64;                // 16 n-tiles
    const int tid = threadIdx.x;
    const int wave = tid >> 6, lane = tid & 63;
    const int quad = lane >> 4, l15 = lane & 15;
    const int wm = (wave >> 1) * 64, wn = (wave & 1) * 32;

    // staging: rows of 64 ushorts (128B = 8 chunks), chunk-XOR pre-swizzled src
    const int ar0 = tid >> 3,          asg0 = (tid & 7) ^ (ar0 & 7);
    const int ar1 = (tid + 256) >> 3,  asg1 = (tid & 7) ^ (ar1 & 7);
    const int ar2 = (tid + 512) >> 3,  asg2 = (tid & 7) ^ (ar2 & 7);
    const int ar3 = (tid + 768) >> 3,  asg3 = (tid & 7) ^ (ar3 & 7);

    floatx4 acc[4][2];
    floatx4 z4 = {0.f, 0.f, 0.f, 0.f};
    for (int mi = 0; mi < 4; mi++)
        for (int ni = 0; ni < 2; ni++) acc[mi][ni] = z4;

    const ushort* Ap0 = A + (size_t)(bm + ar0) * K + asg0 * 8;
    const ushort* Ap1 = A + (size_t)(bm + ar1) * K + asg1 * 8;
    const ushort* Ap2 = A + (size_t)(bm + ar2) * K + asg2 * 8;
    const ushort* Ap3 = A + (size_t)(bm + ar3) * K + asg3 * 8;
    const ushort* Bp0 = Bt + (size_t)(bn + ar0) * K + asg0 * 8;
    const ushort* Bp1 = Bt + (size_t)(bn + ar1) * K + asg1 * 8;

    const int T = 16;                      // K/64
    cp16(Ap0, &As[0][wave * 512]);
    cp16(Ap1, &As[0][2048 + wave * 512]);
    cp16(Ap2, &As[0][4096 + wave * 512]);
    cp16(Ap3, &As[0][6144 + wave * 512]);
    cp16(Bp0, &Bs[0][wave * 512]);
    cp16(Bp1, &Bs[0][2048 + wave * 512]);

    for (int t = 0; t < T; t++) {
        __syncthreads();
        if (t + 1 < T) {
            const int nb = (t + 1) & 1;
            const int k0n = (t + 1) << 6;
            cp16(Ap0 + k0n, &As[nb][wave * 512]);
            cp16(Ap1 + k0n, &As[nb][2048 + wave * 512]);
            cp16(Ap2 + k0n, &As[nb][4096 + wave * 512]);
            cp16(Ap3 + k0n, &As[nb][6144 + wave * 512]);
            cp16(Bp0 + k0n, &Bs[nb][wave * 512]);
            cp16(Bp1 + k0n, &Bs[nb][2048 + wave * 512]);
        }
        const ushort* Ab = As[t & 1];
        const ushort* Bb = Bs[t & 1];
        short8 a0[4], a1[4], b0[2], b1[2];
        for (int mi = 0; mi < 4; mi++) {
            int ra = wm + mi * 16 + l15;
            a0[mi] = *(const short8*)&Ab[ra * 64 + ((quad ^ (ra & 7)) << 3)];
            a1[mi] = *(const short8*)&Ab[ra * 64 + (((quad + 4) ^ (ra & 7)) << 3)];
        }
        for (int ni = 0; ni < 2; ni++) {
            int rb = wn + ni * 16 + l15;
            b0[ni] = *(const short8*)&Bb[rb * 64 + ((quad ^ (rb & 7)) << 3)];
            b1[ni] = *(const short8*)&Bb[rb * 64 + (((quad + 4) ^ (rb & 7)) << 3)];
        }
        for (int mi = 0; mi < 4; mi++)
            for (int ni = 0; ni < 2; ni++) {
                acc[mi][ni] = __builtin_amdgcn_mfma_f32_16x16x32_bf16(
                    a0[mi], b0[ni], acc[mi][ni], 0, 0, 0);
                acc[mi][ni] = __builtin_amdgcn_mfma_f32_16x16x32_bf16(
                    a1[mi], b1[ni], acc[mi][ni], 0, 0, 0);
            }
    }
    for (int mi = 0; mi < 4; mi++)
        for (int ni = 0; ni < 2; ni++)
            for (int r = 0; r < 4; r++) {
                int row = bm + wm + mi * 16 + quad * 4 + r;
                int col = bn + wn + ni * 16 + l15;
                C[(size_t)row * N + col] = acc[mi][ni][r];
            }
}

// ---------------------------------------------------------------------------
// Kernel 4: causal flash attention v16 — round-5 PASSING version, byte-exact
// revert. (Two-strip v19/v20 failed twice with unattributable ~1.35-1.39
// absmax; that design line is closed. Future LDS-traffic attempts will use a
// different implementation: 8 waves x 512 threads, one v16-body per wave.)
// ---------------------------------------------------------------------------
#define LOG2E8 11.541560327111707f   // 8 * log2(e)

__global__ __launch_bounds__(256) void flash_attn(const ushort* __restrict__ Qt,
                                                  const ushort* __restrict__ Kt,
                                                  const ushort* __restrict__ Vb,
                                                  ushort* __restrict__ O) {
    const int id = blockIdx.x;             // 0..1023
    const int xcd = id & 7, r_ = id >> 3;  // r_ 0..127
    const int bh = xcd + ((r_ & 3) << 3);  // 4 bh per XCD
    const int u = r_ >> 2;                 // 0..31
    const int s_ = u >> 3, g = u & 7;
    const int qt = (s_ == 0) ? g : (s_ == 1) ? (15 - g)
                 : (s_ == 2) ? (16 + g) : (31 - g);   // balanced for round-robin
    const int b = bh >> 4, h = bh & 15;
    const int tid = threadIdx.x;
    const int wave = tid >> 6, lane = tid & 63;
    const int quad = lane >> 4, l15 = lane & 15;

    __shared__ ushort Ks[2][64 * 64];   // 16 KB double-buffered K
    __shared__ ushort Vs[64 * 64];      //  8 KB single-buffered V
    __shared__ ushort Ps[4][16 * 64];   //  8 KB, stride 64, chunk-XOR swizzled

    const int ch0 = tid, ch1 = tid + 256;
    const int r0 = ch0 >> 3, sg0 = (ch0 & 7) ^ (r0 & 7);
    const int r1 = ch1 >> 3, sg1 = (ch1 & 7) ^ (r1 & 7);

    const ushort* Kp0 = Kt + ((size_t)bh * 2048 + r0) * 64 + sg0 * 8;
    const ushort* Kp1 = Kt + ((size_t)bh * 2048 + r1) * 64 + sg1 * 8;
    const ushort* Vp0 = Vb + (size_t)bh * 131072 + r0 * 64 + sg0 * 8;
    const ushort* Vp1 = Vb + (size_t)bh * 131072 + r1 * 64 + sg1 * 8;

    floatx4 z4 = {0.f, 0.f, 0.f, 0.f};

    const int q0 = qt * 64;
    const ushort* Qp = Qt + ((size_t)bh * 2048 + q0 + wave * 16 + l15) * 64;
    short8 qf0 = *(const short8*)(Qp + quad * 8);
    short8 qf1 = *(const short8*)(Qp + 32 + quad * 8);

    float rs_acc[4] = {0.f, 0.f, 0.f, 0.f};
    floatx4 o_acc[4];
    for (int ni = 0; ni < 4; ni++) o_acc[ni] = z4;

    // prologue: K[0] via cp16 (async), V[0] into registers
    cp16(Kp0, &Ks[0][wave * 512]);
    cp16(Kp1, &Ks[0][2048 + wave * 512]);
    short8 vA = *(const short8*)Vp0;
    short8 vB = *(const short8*)Vp1;

    for (int kt = 0; kt <= qt; kt++) {
        __syncthreads();                     // K[kt] published; prior PV done
        // publish V[kt] from registers (compiler waits vmcnt for vA/vB)
        *(short8*)&Vs[(unsigned)tid * 8] = vA;
        *(short8*)&Vs[(unsigned)(tid + 256) * 8] = vB;
        if (kt < qt) {                       // prefetch kt+1 during compute
            const int nb2 = (kt + 1) & 1;
            const size_t to = (size_t)(kt + 1) * 4096;
            cp16(Kp0 + to, &Ks[nb2][wave * 512]);
            cp16(Kp1 + to, &Ks[nb2][2048 + wave * 512]);
            vA = *(const short8*)(Vp0 + to);
            vB = *(const short8*)(Vp1 + to);
        }
        const ushort* Kb = Ks[kt & 1];

        floatx4 s_acc[4];
        for (int ni = 0; ni < 4; ni++) s_acc[ni] = z4;
        for (int ni = 0; ni < 4; ni++) {
            int rb = ni * 16 + l15;
            short8 kf0 = *(const short8*)&Kb[rb * 64 + ((quad ^ (rb & 7)) << 3)];
            short8 kf1 = *(const short8*)&Kb[rb * 64 + (((quad + 4) ^ (rb & 7)) << 3)];
            s_acc[ni] = __builtin_amdgcn_mfma_f32_16x16x32_bf16(qf0, kf0, s_acc[ni], 0, 0, 0);
            s_acc[ni] = __builtin_amdgcn_mfma_f32_16x16x32_bf16(qf1, kf1, s_acc[ni], 0, 0, 0);
        }

        const bool diag = (kt == qt);
        for (int ni = 0; ni < 4; ni++) {
            const int col_loc = ni * 16 + l15;
            const int chnk = col_loc >> 3;
            for (int r = 0; r < 4; r++) {
                const int row_l = quad * 4 + r;
                float e = __builtin_amdgcn_exp2f(
                    fmaf(s_acc[ni][r], LOG2E8, -LOG2E8));
                if (diag && col_loc > wave * 16 + row_l) e = 0.f;
                rs_acc[r] += e;
                Ps[wave][row_l * 64 + (((chnk ^ (row_l & 7)) << 3) | (col_loc & 7))] =
                    f2bf_rtz(e);
            }
        }

        __syncthreads();                     // V[kt] stores visible to all waves

        short8 pa0 = *(const short8*)&Ps[wave][l15 * 64 + ((quad ^ (l15 & 7)) << 3)];
        short8 pa1 = *(const short8*)&Ps[wave][l15 * 64 + (((quad + 4) ^ (l15 & 7)) << 3)];
        for (int ni = 0; ni < 4; ni++) {
            int rv = ni * 16 + l15;
            short8 v0 = *(const short8*)&Vs[rv * 64 + ((quad ^ (rv & 7)) << 3)];
            short8 v1 = *(const short8*)&Vs[rv * 64 + (((quad + 4) ^ (rv & 7)) << 3)];
            o_acc[ni] = __builtin_amdgcn_mfma_f32_16x16x32_bf16(pa0, v0, o_acc[ni], 0, 0, 0);
            o_acc[ni] = __builtin_amdgcn_mfma_f32_16x16x32_bf16(pa1, v1, o_acc[ni], 0, 0, 0);
        }
    }

    for (int r = 0; r < 4; r++) {
        float rs = rs_acc[r];
        for (int off = 1; off < 16; off <<= 1) rs += __shfl_xor(rs, off);
        float inv = 1.0f / rs;
        int grow = q0 + wave * 16 + quad * 4 + r;
        size_t rowbase = ((size_t)b * 2048 + grow) * 1024 + h * 64;
        for (int ni = 0; ni < 4; ni++)
            O[rowbase + ni * 16 + l15] = f2bf(o_acc[ni][r] * inv);
    }
}

// ---------------------------------------------------------------------------
extern "C" void kernel_launch(void* const* d_in, const int* in_sizes, int n_in,
                              void* d_out, int out_size, void* d_ws, size_t ws_size,
                              hipStream_t stream) {
    const float* x = (const float*)d_in[0];
    const float* ln_w = (const float*)d_in[1];
    const float* ln_b = (const float*)d_in[2];
    const float* W_qkv = (const float*)d_in[3];
    const float* W_out = (const float*)d_in[4];

    char* w = (char*)d_ws;
    // obuf ALIASES xn: xn is dead after gemm_qkv_fused's last read; flash
    // writes obuf strictly afterwards (stream-ordered). ws = 40 MiB.
    ushort* xn    = (ushort*)(w);                          // 8 MiB
    ushort* obuf  = (ushort*)(w);                          // 8 MiB (alias)
    ushort* WqkvT = (ushort*)(w + (8ull << 20));           // 6 MiB
    ushort* WoutT = (ushort*)(w + (14ull << 20));          // 2 MiB
    ushort* Vb    = (ushort*)(w + (16ull << 20));          // 8 MiB
    ushort* Qt    = (ushort*)(w + (24ull << 20));          // 8 MiB
    ushort* Kt    = (ushort*)(w + (32ull << 20));          // 8 MiB -> 40 MiB total

    prep_w_ln<<<8192, 256, 0, stream>>>(W_qkv, W_out, WqkvT, WoutT, x, ln_w, ln_b, xn);
    gemm_qkv_fused<<<768, 256, 0, stream>>>(xn, WqkvT, Qt, Kt, Vb);
    flash_attn<<<1024, 256, 0, stream>>>(Qt, Kt, Vb, obuf);
    gemm_out<<<512, 256, 0, stream>>>(obuf, WoutT, (float*)d_out);
}